// Round 9
// baseline (107.904 us; speedup 1.0000x reference)
//
#include <hip/hip_runtime.h>

#define BN   8192
#define DIM  128
#define NCLS 128
#define NBLK 1024         // 128 i-strips x 8 j-splits
#define NSTG 16           // per-wave stages: 256 cols / 16

typedef __attribute__((ext_vector_type(8))) short bf16x8;   // 8 x bf16 = 4 VGPRs
typedef __attribute__((ext_vector_type(4))) float f32x4;

// round-to-nearest-even f32 -> bf16
static __device__ __forceinline__ unsigned short f2bf(float x) {
    union { float f; unsigned u; } c; c.f = x;
    unsigned r = c.u + 0x7FFFu + ((c.u >> 16) & 1u);
    return (unsigned short)(r >> 16);
}

static __device__ __forceinline__ bf16x8 ldb8(const unsigned short* p) {
    return *reinterpret_cast<const bf16x8*>(p);
}

// monotone float<->uint key: enc(a) < enc(b)  <=>  a < b
static __device__ __forceinline__ unsigned encf(float f) {
    unsigned u = __float_as_uint(f);
    return (u >> 31) ? ~u : (u | 0x80000000u);
}
static __device__ __forceinline__ float decf(unsigned v) {
    return __uint_as_float((v >> 31) ? (v & 0x7FFFFFFFu) : ~v);
}

// async global->LDS, 16B/lane; LDS dest wave-uniform base + lane*16
static __device__ __forceinline__ void gload_lds16(const unsigned short* g, unsigned short* l) {
    __builtin_amdgcn_global_load_lds(
        (const __attribute__((address_space(1))) unsigned int*)g,
        (__attribute__((address_space(3))) unsigned int*)l, 16, 0, 0);
}

// ---------------- S1: fused sort (block-per-class) + normalize + init -------
__global__ __launch_bounds__(256) void sort_norm(const float* __restrict__ emb,
                                                 const int* __restrict__ labels,
                                                 unsigned short* __restrict__ ebf,
                                                 int2* __restrict__ se,
                                                 unsigned* __restrict__ hp2,
                                                 unsigned* __restrict__ hn2,
                                                 int* __restrict__ done) {
    const int c   = blockIdx.x;              // class id
    const int tid = threadIdx.x;
    if (c == 0 && tid == 0) *done = 0;       // reset last-block counter each call
    __shared__ int sl[256], so[256];
    __shared__ int srcrow[512];              // class size guard (E=64, sd~8)

    int nl = 0, no = 0;
#pragma unroll 8
    for (int k = 0; k < 32; ++k) {           // coalesced label reads
        int lb = labels[k * 256 + tid];
        nl += (lb < c);
        no += (lb == c);
    }
    sl[tid] = nl; so[tid] = no;
    __syncthreads();
    for (int off = 1; off < 256; off <<= 1) {   // Hillis-Steele inclusive scan
        int a1 = 0, a2 = 0;
        if (tid >= off) { a1 = sl[tid - off]; a2 = so[tid - off]; }
        __syncthreads();
        sl[tid] += a1; so[tid] += a2;
        __syncthreads();
    }
    const int offs_c = sl[255];              // rows with label < c
    const int n_c    = so[255];              // class size
    int mypos = so[tid] - no;                // exclusive prefix of own-count
    for (int k = 0; k < 32; ++k) {           // deterministic placement
        int r = k * 256 + tid;
        if (labels[r] == c) srcrow[mypos++] = r;
    }
    __syncthreads();

    const int wave = tid >> 6, lane = tid & 63;
    for (int k = wave; k < n_c; k += 4) {
        int r   = srcrow[k];
        int pos = offs_c + k;
        float2 v = reinterpret_cast<const float2*>(emb + (size_t)r * DIM)[lane];
        float ss = v.x * v.x + v.y * v.y;
#pragma unroll
        for (int m = 1; m < 64; m <<= 1) ss += __shfl_xor(ss, m);
        float inv = 1.0f / fmaxf(sqrtf(ss), 1e-12f);
        ushort2 bv; bv.x = f2bf(v.x * inv); bv.y = f2bf(v.y * inv);
        reinterpret_cast<ushort2*>(ebf + (size_t)pos * DIM)[lane] = bv;
        if (lane == 0) {
            se[pos]  = make_int2(offs_c, offs_c + n_c);
            hp2[pos] = 0xFFFFFFFFu;          // min-key identity
            hn2[pos] = 0u;                   // max-key identity
        }
    }
}

// --------------------------------- main -------------------------------------
// 1024 blocks = 128 i-strips (64 sorted rows) x 8 j-splits; 4 waves, each
// owning a PRIVATE 256-col slice with PRIVATE triple-buffered LDS (3 x 4KB).
// ZERO barriers in the main loop: depth-2 global_load_lds pipeline with
// per-wave counted vmcnt(8). The prefetch is a side-effect instruction the
// compiler CANNOT sink (the R3/R7 pathology), and waves are independent so
// no lockstep (the R4/R5/R8 pathology). 12 waves/CU x depth-2 = 24 in-flight
// loads per CU. launch_bounds(256,3) -> VGPR cap ~170, fits the ~156-reg
// working set without spill. XOR-swizzle pair on stage/read (2-way = free).
// Tracks DOT products: hardest_pos = min dot over same-class (self included,
// self-dot~1 never wins the min), hardest_neg = max dot over rest.
__global__ __launch_bounds__(256, 3) void tri_main(const unsigned short* __restrict__ ebf,
                                                   const int2* __restrict__ se,
                                                   unsigned* __restrict__ hp2,
                                                   unsigned* __restrict__ hn2,
                                                   int* __restrict__ done,
                                                   float* __restrict__ out) {
    __shared__ alignas(16) unsigned short bs[4][3 * 16 * DIM];  // 4 waves x 3 x 4KB
    __shared__ float hpL[4][64], hnL[4][64];
    __shared__ int amlast;

    const int tid  = threadIdx.x;
    const int wave = tid >> 6;
    const int lane = tid & 63;
    const int lr   = lane & 15;        // A row / B col / C col within 16x16 tile
    const int lk   = lane >> 4;        // k-group
    const int iblk  = blockIdx.x >> 3;
    const int jsp   = blockIdx.x & 7;  // == XCD id under round-robin dispatch
    const int i0    = iblk * 64;
    const int jwave = jsp * 1024 + wave * 256;   // this wave's private 256 cols

    // A panel: 4 x 16-row subtiles, K=128 (64 VGPRs, loaded once)
    bf16x8 a[4][4];
#pragma unroll
    for (int t = 0; t < 4; ++t) {
        const unsigned short* ar = ebf + (size_t)(i0 + t * 16 + lr) * DIM + lk * 8;
#pragma unroll
        for (int kk = 0; kk < 4; ++kk) a[t][kk] = ldb8(ar + kk * 32);
    }

    // strip window: union of class ranges of rows i0..i0+63
    const int w0 = __builtin_amdgcn_readfirstlane(se[i0].x);
    const int w1 = __builtin_amdgcn_readfirstlane(se[i0 + 63].y);

    // per-acc-row class range, packed (start<<16 | len)
    int sepk[4][4];
#pragma unroll
    for (int t = 0; t < 4; ++t)
#pragma unroll
        for (int m = 0; m < 4; ++m) {
            int2 q = se[i0 + t * 16 + lk * 4 + m];
            sepk[t][m] = (q.x << 16) | (q.y - q.x);
        }

    float hp[4][4], hn[4][4];                // dot-space: min-pos / max-neg
#pragma unroll
    for (int t = 0; t < 4; ++t)
#pragma unroll
        for (int m = 0; m < 4; ++m) { hp[t][m] = 1e30f; hn[t][m] = -1e30f; }

    unsigned short* mybuf = &bs[wave][0];    // private 12KB, wave-uniform base

    // read offsets: frag(kk) at byte  lr*256 + ((kk*4+lk)^(lr&7))*16
    int perm[4];
#pragma unroll
    for (int kk = 0; kk < 4; ++kk) perm[kk] = (((kk * 4 + lk)) ^ (lr & 7)) << 4;

    // stage s (16 cols) into private buf: 4 gload_lds, source chunk XOR'd so
    // the linear LDS write realizes the swizzled layout (both-sides rule)
    const int colin4 = lane >> 4;            // col within 4-group
    const int pchunk = lane & 15;            // physical 16B chunk
    auto STAGE = [&](int buf, int s) {
        const unsigned short* g0 = ebf + (size_t)(jwave + s * 16) * DIM;
        unsigned short* lb = mybuf + buf * (16 * DIM);
#pragma unroll
        for (int l = 0; l < 4; ++l) {
            const int colg = l * 4 + colin4;
            const int q    = pchunk ^ (colg & 7);
            gload_lds16(g0 + (size_t)colg * DIM + q * 8, lb + l * 4 * DIM);
        }
    };

    STAGE(0, 0); STAGE(1, 1); STAGE(2, 2);   // depth-2 prologue

#pragma unroll
    for (int s = 0; s < NSTG; ++s) {
        // per-wave counted wait: stage-s's 4 loads done; s+1,s+2 stay in flight
        if (s <= NSTG - 3)      { asm volatile("s_waitcnt vmcnt(8)" ::: "memory"); }
        else if (s == NSTG - 2) { asm volatile("s_waitcnt vmcnt(4)" ::: "memory"); }
        else                    { asm volatile("s_waitcnt vmcnt(0)" ::: "memory"); }
        __builtin_amdgcn_sched_barrier(0);

        const char* bb = reinterpret_cast<const char*>(mybuf) + (s % 3) * 4096;
        f32x4 acc[4];
#pragma unroll
        for (int t = 0; t < 4; ++t) acc[t] = f32x4{0.f, 0.f, 0.f, 0.f};

        __builtin_amdgcn_s_setprio(1);
#pragma unroll
        for (int kk = 0; kk < 4; ++kk) {
            bf16x8 bk = *reinterpret_cast<const bf16x8*>(bb + lr * 256 + perm[kk]);
#pragma unroll
            for (int t = 0; t < 4; ++t)
                acc[t] = __builtin_amdgcn_mfma_f32_16x16x32_bf16(a[t][kk], bk, acc[t], 0, 0, 0);
        }
        __builtin_amdgcn_s_setprio(0);

        // all ds_reads of this buffer complete before its DMA overwrite issues
        asm volatile("s_waitcnt lgkmcnt(0)" ::: "memory");
        __builtin_amdgcn_sched_barrier(0);
        if (s + 3 < NSTG) STAGE(s % 3, s + 3);

        const int j0 = jwave + s * 16;
        if (j0 + 16 <= w0 || j0 >= w1) {     // pure-negative tile (common)
#pragma unroll
            for (int t = 0; t < 4; ++t)
#pragma unroll
                for (int m = 0; m < 4; ++m) hn[t][m] = fmaxf(hn[t][m], acc[t][m]);
        } else {                             // mixed tile (near diagonal, rare)
            const int jc = j0 + lr;
#pragma unroll
            for (int t = 0; t < 4; ++t)
#pragma unroll
                for (int m = 0; m < 4; ++m) {
                    int  st  = sepk[t][m] >> 16;
                    int  len = sepk[t][m] & 0xFFFF;
                    bool pos = (unsigned)(jc - st) < (unsigned)len;
                    hp[t][m] = pos ? fminf(hp[t][m], acc[t][m]) : hp[t][m];
                    hn[t][m] = pos ? hn[t][m] : fmaxf(hn[t][m], acc[t][m]);
                }
        }
    }

    // reduce across the 16 lanes sharing accum rows, then across waves in LDS
#pragma unroll
    for (int t = 0; t < 4; ++t)
#pragma unroll
        for (int m = 0; m < 4; ++m) {
            float p = hp[t][m], n = hn[t][m];
#pragma unroll
            for (int sft = 1; sft < 16; sft <<= 1) {
                p = fminf(p, __shfl_xor(p, sft));
                n = fmaxf(n, __shfl_xor(n, sft));
            }
            if (lr == 0) {
                int r = t * 16 + lk * 4 + m;
                hpL[wave][r] = p;
                hnL[wave][r] = n;
            }
        }
    __syncthreads();
    if (tid < 64) {
        float p = fminf(fminf(hpL[0][tid], hpL[1][tid]), fminf(hpL[2][tid], hpL[3][tid]));
        float n = fmaxf(fmaxf(hnL[0][tid], hnL[1][tid]), fmaxf(hnL[2][tid], hnL[3][tid]));
        atomicMin(&hp2[i0 + tid], encf(p));
        atomicMax(&hn2[i0 + tid], encf(n));
    }
    __syncthreads();                         // all this block's atomics performed

    // ---- folded finalize: last block to arrive reduces hp2/hn2 -> out[0] ----
    if (tid == 0) {
        __threadfence();                     // release our atomics
        amlast = (atomicAdd(done, 1) == NBLK - 1);
    }
    __syncthreads();
    if (!amlast) return;
    __threadfence();                         // acquire all blocks' atomics

    float sum = 0.f;
#pragma unroll
    for (int it = 0; it < BN / (256 * 4); ++it) {    // 8 iters, uint4 per thread
        int base = (it * 256 + tid) * 4;
        uint4 pv = *reinterpret_cast<const uint4*>(&hp2[base]);
        uint4 nv = *reinterpret_cast<const uint4*>(&hn2[base]);
        unsigned pa[4] = {pv.x, pv.y, pv.z, pv.w};
        unsigned na[4] = {nv.x, nv.y, nv.z, nv.w};
#pragma unroll
        for (int e = 0; e < 4; ++e) {
            float pd = decf(pa[e]);          // min dot over pos
            float nd = decf(na[e]);          // max dot over neg
            float hpv = sqrtf(fmaxf(2.0f - 2.0f * pd, 0.f));
            float hnv = sqrtf(fmaxf(2.0f - 2.0f * nd, 0.f));
            // relu(hp - hn + 0.5*(1+hp)) = relu(1.5*hp + 0.5 - hn)
            sum += fmaxf(fmaf(1.5f, hpv, 0.5f) - hnv, 0.f);
        }
    }
    float* red = &hpL[0][0];                 // reuse 256 floats of LDS
    red[tid] = sum;
    __syncthreads();
    for (int s2 = 128; s2 > 0; s2 >>= 1) {
        if (tid < s2) red[tid] += red[tid + s2];
        __syncthreads();
    }
    if (tid == 0) out[0] = red[0] * (1.0f / (float)BN);    // all rows valid
}

// ---------------------------------------------------------------- launch
extern "C" void kernel_launch(void* const* d_in, const int* in_sizes, int n_in,
                              void* d_out, int out_size, void* d_ws, size_t ws_size,
                              hipStream_t stream) {
    const float* emb    = (const float*)d_in[0];
    const int*   labels = (const int*)d_in[1];
    float* out = (float*)d_out;

    char* ws = (char*)d_ws;
    unsigned short* ebf = (unsigned short*)ws;                            // 2 MiB sorted bf16 E
    int2*     se   = (int2*)    (ws + 2u * 1024u * 1024u);                // 64 KiB class ranges
    unsigned* hp2  = (unsigned*)(ws + 2u * 1024u * 1024u + 64u * 1024u);  // 32 KiB
    unsigned* hn2  = (unsigned*)(ws + 2u * 1024u * 1024u + 96u * 1024u);  // 32 KiB
    int*      done = (int*)     (ws + 2u * 1024u * 1024u + 128u * 1024u); // 4 B

    hipLaunchKernelGGL(sort_norm, dim3(NCLS), dim3(256), 0, stream, emb, labels, ebf, se, hp2, hn2, done);
    hipLaunchKernelGGL(tri_main,  dim3(NBLK), dim3(256), 0, stream, ebf, se, hp2, hn2, done, out);
}

// Round 10
// 78.595 us; speedup vs baseline: 1.3729x; 1.3729x over previous
//
#include <hip/hip_runtime.h>

#define BN   8192
#define DIM  128
#define NCLS 128
#define NBLK 1024         // 128 i-strips x 8 j-splits
#define NSTG 16           // per-wave stages: 256 cols / 16

typedef __attribute__((ext_vector_type(8))) short bf16x8;   // 8 x bf16 = 4 VGPRs
typedef __attribute__((ext_vector_type(4))) float f32x4;

// round-to-nearest-even f32 -> bf16
static __device__ __forceinline__ unsigned short f2bf(float x) {
    union { float f; unsigned u; } c; c.f = x;
    unsigned r = c.u + 0x7FFFu + ((c.u >> 16) & 1u);
    return (unsigned short)(r >> 16);
}

static __device__ __forceinline__ bf16x8 ldb8(const unsigned short* p) {
    return *reinterpret_cast<const bf16x8*>(p);
}

// monotone float<->uint key: enc(a) < enc(b)  <=>  a < b
static __device__ __forceinline__ unsigned encf(float f) {
    unsigned u = __float_as_uint(f);
    return (u >> 31) ? ~u : (u | 0x80000000u);
}
static __device__ __forceinline__ float decf(unsigned v) {
    return __uint_as_float((v >> 31) ? (v & 0x7FFFFFFFu) : ~v);
}

// async global->LDS, 16B/lane; LDS dest wave-uniform base + lane*16
static __device__ __forceinline__ void gload_lds16(const unsigned short* g, unsigned short* l) {
    __builtin_amdgcn_global_load_lds(
        (const __attribute__((address_space(1))) unsigned int*)g,
        (__attribute__((address_space(3))) unsigned int*)l, 16, 0, 0);
}

// ---------------- S1: fused sort (block-per-class) + normalize + init -------
__global__ __launch_bounds__(256) void sort_norm(const float* __restrict__ emb,
                                                 const int* __restrict__ labels,
                                                 unsigned short* __restrict__ ebf,
                                                 int2* __restrict__ se,
                                                 unsigned* __restrict__ hp2,
                                                 unsigned* __restrict__ hn2,
                                                 int* __restrict__ done) {
    const int c   = blockIdx.x;              // class id
    const int tid = threadIdx.x;
    if (c == 0 && tid == 0) *done = 0;       // reset last-block counter each call
    __shared__ int sl[256], so[256];
    __shared__ int srcrow[512];              // class size guard (E=64, sd~8)

    int nl = 0, no = 0;
#pragma unroll 8
    for (int k = 0; k < 32; ++k) {           // coalesced label reads
        int lb = labels[k * 256 + tid];
        nl += (lb < c);
        no += (lb == c);
    }
    sl[tid] = nl; so[tid] = no;
    __syncthreads();
    for (int off = 1; off < 256; off <<= 1) {   // Hillis-Steele inclusive scan
        int a1 = 0, a2 = 0;
        if (tid >= off) { a1 = sl[tid - off]; a2 = so[tid - off]; }
        __syncthreads();
        sl[tid] += a1; so[tid] += a2;
        __syncthreads();
    }
    const int offs_c = sl[255];              // rows with label < c
    const int n_c    = so[255];              // class size
    int mypos = so[tid] - no;                // exclusive prefix of own-count
    for (int k = 0; k < 32; ++k) {           // deterministic placement
        int r = k * 256 + tid;
        if (labels[r] == c) srcrow[mypos++] = r;
    }
    __syncthreads();

    const int wave = tid >> 6, lane = tid & 63;
    for (int k = wave; k < n_c; k += 4) {
        int r   = srcrow[k];
        int pos = offs_c + k;
        float2 v = reinterpret_cast<const float2*>(emb + (size_t)r * DIM)[lane];
        float ss = v.x * v.x + v.y * v.y;
#pragma unroll
        for (int m = 1; m < 64; m <<= 1) ss += __shfl_xor(ss, m);
        float inv = 1.0f / fmaxf(sqrtf(ss), 1e-12f);
        ushort2 bv; bv.x = f2bf(v.x * inv); bv.y = f2bf(v.y * inv);
        reinterpret_cast<ushort2*>(ebf + (size_t)pos * DIM)[lane] = bv;
        if (lane == 0) {
            se[pos]  = make_int2(offs_c, offs_c + n_c);
            hp2[pos] = 0xFFFFFFFFu;          // min-key identity
            hn2[pos] = 0u;                   // max-key identity
        }
    }
}

// --------------------------------- main -------------------------------------
// 1024 blocks = 128 i-strips (64 sorted rows) x 8 j-splits; 4 waves, each
// owning a PRIVATE 256-col slice with PRIVATE triple-buffered LDS (3 x 4KB).
// ZERO barriers in the main loop; depth-2 global_load_lds pipeline (the
// prefetch is a side-effect op the compiler cannot sink) with per-wave
// counted vmcnt. Allocator fixes vs R9: waves_per_eu(3,3) pins the occupancy
// tier (max=3 removes the incentive to squeeze/spill below ~168 VGPR);
// unroll-1 main loop with runtime LDS byte-offset rotation (small code, low
// pressure; rule-#20 only bans runtime-indexed REGISTER arrays, LDS addr
// arithmetic is fine); sepk regs dropped (se read inside the rare branch).
// Tracks DOT products: hardest_pos = min dot over same-class (self included,
// self-dot~1 never wins the min), hardest_neg = max dot over rest.
__global__ __launch_bounds__(256) __attribute__((amdgpu_waves_per_eu(3, 3)))
void tri_main(const unsigned short* __restrict__ ebf,
              const int2* __restrict__ se,
              unsigned* __restrict__ hp2,
              unsigned* __restrict__ hn2,
              int* __restrict__ done,
              float* __restrict__ out) {
    __shared__ alignas(16) unsigned short bs[4][3 * 16 * DIM];  // 4 waves x 3 x 4KB
    __shared__ float hpL[4][64], hnL[4][64];
    __shared__ int amlast;

    const int tid  = threadIdx.x;
    const int wave = tid >> 6;
    const int lane = tid & 63;
    const int lr   = lane & 15;        // A row / B col / C col within 16x16 tile
    const int lk   = lane >> 4;        // k-group
    const int iblk  = blockIdx.x >> 3;
    const int jsp   = blockIdx.x & 7;  // == XCD id under round-robin dispatch
    const int i0    = iblk * 64;
    const int jwave = jsp * 1024 + wave * 256;   // this wave's private 256 cols

    // A panel: 4 x 16-row subtiles, K=128 (64 VGPRs, loaded once)
    bf16x8 a[4][4];
#pragma unroll
    for (int t = 0; t < 4; ++t) {
        const unsigned short* ar = ebf + (size_t)(i0 + t * 16 + lr) * DIM + lk * 8;
#pragma unroll
        for (int kk = 0; kk < 4; ++kk) a[t][kk] = ldb8(ar + kk * 32);
    }

    // strip window: union of class ranges of rows i0..i0+63
    const int w0 = __builtin_amdgcn_readfirstlane(se[i0].x);
    const int w1 = __builtin_amdgcn_readfirstlane(se[i0 + 63].y);

    float hp[4][4], hn[4][4];                // dot-space: min-pos / max-neg
#pragma unroll
    for (int t = 0; t < 4; ++t)
#pragma unroll
        for (int m = 0; m < 4; ++m) { hp[t][m] = 1e30f; hn[t][m] = -1e30f; }

    unsigned short* mybuf = &bs[wave][0];    // private 12KB, wave-uniform base

    // read offsets: frag(kk) at byte  lr*256 + ((kk*4+lk)^(lr&7))*16
    int perm[4];
#pragma unroll
    for (int kk = 0; kk < 4; ++kk) perm[kk] = (((kk * 4 + lk)) ^ (lr & 7)) << 4;

    // stage s (16 cols) into private buf at byte offset bufoff: 4 gload_lds,
    // source chunk XOR'd so the linear LDS write realizes the swizzled layout
    const int colin4 = lane >> 4;            // col within 4-group
    const int pchunk = lane & 15;            // physical 16B chunk
    auto STAGE = [&](int bufoff, int s) {
        const unsigned short* g0 = ebf + (size_t)(jwave + s * 16) * DIM;
        unsigned short* lb = (unsigned short*)((char*)mybuf + bufoff);
#pragma unroll
        for (int l = 0; l < 4; ++l) {
            const int colg = l * 4 + colin4;
            const int q    = pchunk ^ (colg & 7);
            gload_lds16(g0 + (size_t)colg * DIM + q * 8, lb + l * 4 * DIM);
        }
    };

    STAGE(0, 0); STAGE(4096, 1); STAGE(8192, 2);   // depth-2 prologue

    int curoff = 0;
#pragma unroll 1
    for (int s = 0; s < NSTG; ++s) {
        // per-wave counted wait: stage-s's 4 loads done; s+1,s+2 stay in flight
        if (s <= NSTG - 3)      { asm volatile("s_waitcnt vmcnt(8)" ::: "memory"); }
        else if (s == NSTG - 2) { asm volatile("s_waitcnt vmcnt(4)" ::: "memory"); }
        else                    { asm volatile("s_waitcnt vmcnt(0)" ::: "memory"); }
        __builtin_amdgcn_sched_barrier(0);

        const char* bb = reinterpret_cast<const char*>(mybuf) + curoff;
        bf16x8 b0 = *reinterpret_cast<const bf16x8*>(bb + lr * 256 + perm[0]);
        bf16x8 b1 = *reinterpret_cast<const bf16x8*>(bb + lr * 256 + perm[1]);
        bf16x8 b2 = *reinterpret_cast<const bf16x8*>(bb + lr * 256 + perm[2]);
        bf16x8 b3 = *reinterpret_cast<const bf16x8*>(bb + lr * 256 + perm[3]);

        f32x4 acc[4];
#pragma unroll
        for (int t = 0; t < 4; ++t) acc[t] = f32x4{0.f, 0.f, 0.f, 0.f};

        __builtin_amdgcn_s_setprio(1);
#pragma unroll
        for (int t = 0; t < 4; ++t) {
            acc[t] = __builtin_amdgcn_mfma_f32_16x16x32_bf16(a[t][0], b0, acc[t], 0, 0, 0);
            acc[t] = __builtin_amdgcn_mfma_f32_16x16x32_bf16(a[t][1], b1, acc[t], 0, 0, 0);
            acc[t] = __builtin_amdgcn_mfma_f32_16x16x32_bf16(a[t][2], b2, acc[t], 0, 0, 0);
            acc[t] = __builtin_amdgcn_mfma_f32_16x16x32_bf16(a[t][3], b3, acc[t], 0, 0, 0);
        }
        __builtin_amdgcn_s_setprio(0);

        // all ds_reads of this buffer complete before its DMA overwrite issues
        asm volatile("s_waitcnt lgkmcnt(0)" ::: "memory");
        __builtin_amdgcn_sched_barrier(0);
        if (s + 3 < NSTG) STAGE(curoff, s + 3);

        const int j0 = jwave + s * 16;
        if (j0 + 16 <= w0 || j0 >= w1) {     // pure-negative tile (common)
#pragma unroll
            for (int t = 0; t < 4; ++t)
#pragma unroll
                for (int m = 0; m < 4; ++m) hn[t][m] = fmaxf(hn[t][m], acc[t][m]);
        } else {                             // mixed tile (near diagonal, rare)
            const int jc = j0 + lr;
#pragma unroll
            for (int t = 0; t < 4; ++t)
#pragma unroll
                for (int m = 0; m < 4; ++m) {
                    // volatile: keep these rare-path loads inside the branch
                    volatile const int2* vq = &se[i0 + t * 16 + lk * 4 + m];
                    const int qs = vq->x, qe = vq->y;
                    bool pos = (jc >= qs) && (jc < qe);
                    hp[t][m] = pos ? fminf(hp[t][m], acc[t][m]) : hp[t][m];
                    hn[t][m] = pos ? hn[t][m] : fmaxf(hn[t][m], acc[t][m]);
                }
        }
        curoff = (curoff == 8192) ? 0 : curoff + 4096;
    }

    // reduce across the 16 lanes sharing accum rows, then across waves in LDS
#pragma unroll
    for (int t = 0; t < 4; ++t)
#pragma unroll
        for (int m = 0; m < 4; ++m) {
            float p = hp[t][m], n = hn[t][m];
#pragma unroll
            for (int sft = 1; sft < 16; sft <<= 1) {
                p = fminf(p, __shfl_xor(p, sft));
                n = fmaxf(n, __shfl_xor(n, sft));
            }
            if (lr == 0) {
                int r = t * 16 + lk * 4 + m;
                hpL[wave][r] = p;
                hnL[wave][r] = n;
            }
        }
    __syncthreads();
    if (tid < 64) {
        float p = fminf(fminf(hpL[0][tid], hpL[1][tid]), fminf(hpL[2][tid], hpL[3][tid]));
        float n = fmaxf(fmaxf(hnL[0][tid], hnL[1][tid]), fmaxf(hnL[2][tid], hnL[3][tid]));
        atomicMin(&hp2[i0 + tid], encf(p));
        atomicMax(&hn2[i0 + tid], encf(n));
    }
    __syncthreads();                         // all this block's atomics performed

    // ---- folded finalize: last block to arrive reduces hp2/hn2 -> out[0] ----
    if (tid == 0) {
        __threadfence();                     // release our atomics
        amlast = (atomicAdd(done, 1) == NBLK - 1);
    }
    __syncthreads();
    if (!amlast) return;
    __threadfence();                         // acquire all blocks' atomics

    float sum = 0.f;
#pragma unroll
    for (int it = 0; it < BN / (256 * 4); ++it) {    // 8 iters, uint4 per thread
        int base = (it * 256 + tid) * 4;
        uint4 pv = *reinterpret_cast<const uint4*>(&hp2[base]);
        uint4 nv = *reinterpret_cast<const uint4*>(&hn2[base]);
        unsigned pa[4] = {pv.x, pv.y, pv.z, pv.w};
        unsigned na[4] = {nv.x, nv.y, nv.z, nv.w};
#pragma unroll
        for (int e = 0; e < 4; ++e) {
            float pd = decf(pa[e]);          // min dot over pos
            float nd = decf(na[e]);          // max dot over neg
            float hpv = sqrtf(fmaxf(2.0f - 2.0f * pd, 0.f));
            float hnv = sqrtf(fmaxf(2.0f - 2.0f * nd, 0.f));
            // relu(hp - hn + 0.5*(1+hp)) = relu(1.5*hp + 0.5 - hn)
            sum += fmaxf(fmaf(1.5f, hpv, 0.5f) - hnv, 0.f);
        }
    }
    float* red = &hpL[0][0];                 // reuse 256 floats of LDS
    red[tid] = sum;
    __syncthreads();
    for (int s2 = 128; s2 > 0; s2 >>= 1) {
        if (tid < s2) red[tid] += red[tid + s2];
        __syncthreads();
    }
    if (tid == 0) out[0] = red[0] * (1.0f / (float)BN);    // all rows valid
}

// ---------------------------------------------------------------- launch
extern "C" void kernel_launch(void* const* d_in, const int* in_sizes, int n_in,
                              void* d_out, int out_size, void* d_ws, size_t ws_size,
                              hipStream_t stream) {
    const float* emb    = (const float*)d_in[0];
    const int*   labels = (const int*)d_in[1];
    float* out = (float*)d_out;

    char* ws = (char*)d_ws;
    unsigned short* ebf = (unsigned short*)ws;                            // 2 MiB sorted bf16 E
    int2*     se   = (int2*)    (ws + 2u * 1024u * 1024u);                // 64 KiB class ranges
    unsigned* hp2  = (unsigned*)(ws + 2u * 1024u * 1024u + 64u * 1024u);  // 32 KiB
    unsigned* hn2  = (unsigned*)(ws + 2u * 1024u * 1024u + 96u * 1024u);  // 32 KiB
    int*      done = (int*)     (ws + 2u * 1024u * 1024u + 128u * 1024u); // 4 B

    hipLaunchKernelGGL(sort_norm, dim3(NCLS), dim3(256), 0, stream, emb, labels, ebf, se, hp2, hn2, done);
    hipLaunchKernelGGL(tri_main,  dim3(NBLK), dim3(256), 0, stream, ebf, se, hp2, hn2, done, out);
}

// Round 11
// 64.417 us; speedup vs baseline: 1.6751x; 1.2201x over previous
//
#include <hip/hip_runtime.h>

#define BN   8192
#define DIM  128
#define NCLS 128
#define NBLK 1024         // 64 col-blocks (128 cols) x 16 i-splits (512 rows)
#define NSTR 8            // strips of 64 rows per block

typedef __attribute__((ext_vector_type(8))) short bf16x8;   // 8 x bf16 = 4 VGPRs
typedef __attribute__((ext_vector_type(4))) float f32x4;

// round-to-nearest-even f32 -> bf16
static __device__ __forceinline__ unsigned short f2bf(float x) {
    union { float f; unsigned u; } c; c.f = x;
    unsigned r = c.u + 0x7FFFu + ((c.u >> 16) & 1u);
    return (unsigned short)(r >> 16);
}

static __device__ __forceinline__ bf16x8 ldb8(const unsigned short* p) {
    return *reinterpret_cast<const bf16x8*>(p);
}

// monotone float<->uint key: enc(a) < enc(b)  <=>  a < b
static __device__ __forceinline__ unsigned encf(float f) {
    unsigned u = __float_as_uint(f);
    return (u >> 31) ? ~u : (u | 0x80000000u);
}
static __device__ __forceinline__ float decf(unsigned v) {
    return __uint_as_float((v >> 31) ? (v & 0x7FFFFFFFu) : ~v);
}

// async global->LDS, 16B/lane; LDS dest wave-uniform base + lane*16
static __device__ __forceinline__ void gload_lds16(const unsigned short* g, unsigned short* l) {
    __builtin_amdgcn_global_load_lds(
        (const __attribute__((address_space(1))) unsigned int*)g,
        (__attribute__((address_space(3))) unsigned int*)l, 16, 0, 0);
}

// ---------------- S1: fused sort (block-per-class) + normalize + init -------
// labels cached in LDS (one global pass); block c computes its class offset,
// collects rows deterministically, normalizes + scatters bf16 rows.
__global__ __launch_bounds__(256) void sort_norm(const float* __restrict__ emb,
                                                 const int* __restrict__ labels,
                                                 unsigned short* __restrict__ ebf,
                                                 int2* __restrict__ se,
                                                 unsigned* __restrict__ hp2,
                                                 unsigned* __restrict__ hn2,
                                                 int* __restrict__ done) {
    const int c   = blockIdx.x;              // class id
    const int tid = threadIdx.x;
    if (c == 0 && tid == 0) *done = 0;       // reset last-block counter each call
    __shared__ int slab[BN];                 // 32 KiB label cache
    __shared__ int sl[256], so[256];
    __shared__ int srcrow[512];              // class size guard (E=64, sd~8)

#pragma unroll 8
    for (int k = 0; k < 32; ++k) {           // one coalesced label pass
        int idx = k * 256 + tid;
        slab[idx] = labels[idx];
    }
    __syncthreads();

    int nl = 0, no = 0;
#pragma unroll 8
    for (int k = 0; k < 32; ++k) {
        int lb = slab[k * 256 + tid];
        nl += (lb < c);
        no += (lb == c);
    }
    sl[tid] = nl; so[tid] = no;
    __syncthreads();
    for (int off = 1; off < 256; off <<= 1) {   // Hillis-Steele inclusive scan
        int a1 = 0, a2 = 0;
        if (tid >= off) { a1 = sl[tid - off]; a2 = so[tid - off]; }
        __syncthreads();
        sl[tid] += a1; so[tid] += a2;
        __syncthreads();
    }
    const int offs_c = sl[255];              // rows with label < c
    const int n_c    = so[255];              // class size
    int mypos = so[tid] - no;                // exclusive prefix of own-count
    for (int k = 0; k < 32; ++k) {           // deterministic placement
        int r = k * 256 + tid;
        if (slab[r] == c) srcrow[mypos++] = r;
    }
    __syncthreads();

    const int wave = tid >> 6, lane = tid & 63;
    for (int k = wave; k < n_c; k += 4) {
        int r   = srcrow[k];
        int pos = offs_c + k;
        float2 v = reinterpret_cast<const float2*>(emb + (size_t)r * DIM)[lane];
        float ss = v.x * v.x + v.y * v.y;
#pragma unroll
        for (int m = 1; m < 64; m <<= 1) ss += __shfl_xor(ss, m);
        float inv = 1.0f / fmaxf(sqrtf(ss), 1e-12f);
        ushort2 bv; bv.x = f2bf(v.x * inv); bv.y = f2bf(v.y * inv);
        reinterpret_cast<ushort2*>(ebf + (size_t)pos * DIM)[lane] = bv;
        if (lane == 0) {
            se[pos]  = make_int2(offs_c, offs_c + n_c);
            hp2[pos] = 0xFFFFFFFFu;          // min-key identity
            hn2[pos] = 0u;                   // max-key identity
        }
    }
}

// --------------------------------- main -------------------------------------
// FLIPPED operands (symmetry: column stats == row stats since d(i,j)=d(j,i)).
// 1024 blocks = 64 col-blocks x 16 i-splits. Each wave owns 32 FIXED columns:
// B fragments = 32 regs loaded once; stats = 4 lane-local scalars (hp/hn for
// 2 cols per lane); col class-range = 4 loop-invariant regs -> branch-free
// epilogue, no se[] loads in the loop, no end-of-tile shuffle storm.
// A row-strips (64 rows) stream through double-buffered LDS shared by all 4
// waves (m97-canonical gload_lds + 1 barrier/strip); each LDS frag feeds 2
// MFMA. Natural VGPR pressure ~105 = the allocator's preferred tier: nothing
// for it to sink or spill (the R2-R10 pathology). 4 blocks/CU x 4 waves TLP.
// hardest_pos[c] = min dot over same-class rows (self-dot~1 never the min);
// hardest_neg[c] = max dot over rest.
__global__ __launch_bounds__(256) void tri_main(const unsigned short* __restrict__ ebf,
                                                const int2* __restrict__ se,
                                                unsigned* __restrict__ hp2,
                                                unsigned* __restrict__ hn2,
                                                int* __restrict__ done,
                                                float* __restrict__ out) {
    __shared__ alignas(16) unsigned short as_[2][64 * DIM];   // 2 x 16 KiB A strips
    __shared__ float red[256];
    __shared__ int amlast;

    const int tid  = threadIdx.x;
    const int wave = tid >> 6;
    const int lane = tid & 63;
    const int lr   = lane & 15;        // col within 16-subtile / A row in frag
    const int lk   = lane >> 4;        // k-group / C row-group
    const int jb   = blockIdx.x >> 4;  // col-block (128 cols)
    const int isp  = blockIdx.x & 15;  // i-split (512 rows)
    const int jc0  = jb * 128 + wave * 32;       // wave's col base (32 cols)
    const int rb0  = isp * 512;                  // block's row base

    // B fragments: 2 col-subtiles x 4 k-steps = 32 VGPRs, loaded once (L2-hit)
    bf16x8 b[2][4];
#pragma unroll
    for (int cs = 0; cs < 2; ++cs)
#pragma unroll
        for (int kk = 0; kk < 4; ++kk)
            b[cs][kk] = ldb8(ebf + (size_t)(jc0 + cs * 16 + lr) * DIM + kk * 32 + lk * 8);

    // lane's 2 columns' class ranges (loop-invariant)
    const int2 q0 = se[jc0 + lr];
    const int2 q1 = se[jc0 + 16 + lr];
    const int cs0s = q0.x, cs0l = q0.y - q0.x;
    const int cs1s = q1.x, cs1l = q1.y - q1.x;

    float hp0 = 1e30f, hn0 = -1e30f;         // dot-space: min-pos / max-neg
    float hp1 = 1e30f, hn1 = -1e30f;

    // A ds_read offsets: frag(t,kk) at byte (t*16+lr)*256 + perm[kk] (+parity)
    int perm[4];
#pragma unroll
    for (int kk = 0; kk < 4; ++kk) perm[kk] = ((kk * 4 + lk) ^ (lr & 7)) << 4;

    // staging: wave stages rows [wave*16, wave*16+16) of the strip; source
    // chunk XOR'd by (row&7) so the linear LDS write realizes the swizzle
    const int rloc  = lane >> 4;             // row within 4-group
    const int chunk = lane & 15;             // physical 16B chunk
    auto STAGE = [&](int buf, int s) {
        const unsigned short* g0 = ebf + (size_t)(rb0 + s * 64) * DIM;
        unsigned short* lb = &as_[buf][wave * 16 * DIM];
#pragma unroll
        for (int l = 0; l < 4; ++l) {
            const int row = l * 4 + rloc;
            gload_lds16(g0 + (size_t)(wave * 16 + row) * DIM + ((chunk ^ (row & 7)) * 8),
                        lb + l * 4 * DIM);
        }
    };

    STAGE(0, 0);
    __syncthreads();

    for (int s = 0; s < NSTR; ++s) {
        if (s < NSTR - 1) STAGE((s + 1) & 1, s + 1);   // async prefetch next strip

        const char* bb = reinterpret_cast<const char*>(&as_[s & 1][0]);
        f32x4 acc[2][4];
#pragma unroll
        for (int cs = 0; cs < 2; ++cs)
#pragma unroll
            for (int t = 0; t < 4; ++t) acc[cs][t] = f32x4{0.f, 0.f, 0.f, 0.f};

        __builtin_amdgcn_s_setprio(1);
#pragma unroll
        for (int t = 0; t < 4; ++t)
#pragma unroll
            for (int kk = 0; kk < 4; ++kk) {
                bf16x8 af = *reinterpret_cast<const bf16x8*>(bb + (t * 16 + lr) * 256 + perm[kk]);
                acc[0][t] = __builtin_amdgcn_mfma_f32_16x16x32_bf16(af, b[0][kk], acc[0][t], 0, 0, 0);
                acc[1][t] = __builtin_amdgcn_mfma_f32_16x16x32_bf16(af, b[1][kk], acc[1][t], 0, 0, 0);
            }
        __builtin_amdgcn_s_setprio(0);

        // branch-free epilogue: C layout col=lane&15, row=lk*4+m (+t*16)
        const int rb = rb0 + s * 64;
#pragma unroll
        for (int t = 0; t < 4; ++t)
#pragma unroll
            for (int m = 0; m < 4; ++m) {
                const int rowg = rb + t * 16 + lk * 4 + m;
                const float d0 = acc[0][t][m];
                const float d1 = acc[1][t][m];
                const bool p0 = (unsigned)(rowg - cs0s) < (unsigned)cs0l;
                const bool p1 = (unsigned)(rowg - cs1s) < (unsigned)cs1l;
                hp0 = p0 ? fminf(hp0, d0) : hp0;
                hn0 = p0 ? hn0 : fmaxf(hn0, d0);
                hp1 = p1 ? fminf(hp1, d1) : hp1;
                hn1 = p1 ? hn1 : fmaxf(hn1, d1);
            }

        __syncthreads();   // strip s reads done by all waves + strip s+1 landed
    }

    // combine the 4 lk-groups (lanes lr, lr+16, lr+32, lr+48 share columns)
#pragma unroll
    for (int sft = 16; sft < 64; sft <<= 1) {
        hp0 = fminf(hp0, __shfl_xor(hp0, sft));
        hn0 = fmaxf(hn0, __shfl_xor(hn0, sft));
        hp1 = fminf(hp1, __shfl_xor(hp1, sft));
        hn1 = fmaxf(hn1, __shfl_xor(hn1, sft));
    }
    if (lane < 16) {
        atomicMin(&hp2[jc0 + lane], encf(hp0));
        atomicMax(&hn2[jc0 + lane], encf(hn0));
        atomicMin(&hp2[jc0 + 16 + lane], encf(hp1));
        atomicMax(&hn2[jc0 + 16 + lane], encf(hn1));
    }
    __syncthreads();                         // all this block's atomics performed

    // ---- folded finalize: last block to arrive reduces hp2/hn2 -> out[0] ----
    if (tid == 0) {
        __threadfence();                     // release our atomics
        amlast = (atomicAdd(done, 1) == NBLK - 1);
    }
    __syncthreads();
    if (!amlast) return;
    __threadfence();                         // acquire all blocks' atomics

    float sum = 0.f;
#pragma unroll
    for (int it = 0; it < BN / (256 * 4); ++it) {    // 8 iters, uint4 per thread
        int base = (it * 256 + tid) * 4;
        uint4 pv = *reinterpret_cast<const uint4*>(&hp2[base]);
        uint4 nv = *reinterpret_cast<const uint4*>(&hn2[base]);
        unsigned pa[4] = {pv.x, pv.y, pv.z, pv.w};
        unsigned na[4] = {nv.x, nv.y, nv.z, nv.w};
#pragma unroll
        for (int e = 0; e < 4; ++e) {
            float pd = decf(pa[e]);          // min dot over pos
            float nd = decf(na[e]);          // max dot over neg
            float hpv = sqrtf(fmaxf(2.0f - 2.0f * pd, 0.f));
            float hnv = sqrtf(fmaxf(2.0f - 2.0f * nd, 0.f));
            // relu(hp - hn + 0.5*(1+hp)) = relu(1.5*hp + 0.5 - hn)
            sum += fmaxf(fmaf(1.5f, hpv, 0.5f) - hnv, 0.f);
        }
    }
    red[tid] = sum;
    __syncthreads();
    for (int s2 = 128; s2 > 0; s2 >>= 1) {
        if (tid < s2) red[tid] += red[tid + s2];
        __syncthreads();
    }
    if (tid == 0) out[0] = red[0] * (1.0f / (float)BN);    // all rows valid
}

// ---------------------------------------------------------------- launch
extern "C" void kernel_launch(void* const* d_in, const int* in_sizes, int n_in,
                              void* d_out, int out_size, void* d_ws, size_t ws_size,
                              hipStream_t stream) {
    const float* emb    = (const float*)d_in[0];
    const int*   labels = (const int*)d_in[1];
    float* out = (float*)d_out;

    char* ws = (char*)d_ws;
    unsigned short* ebf = (unsigned short*)ws;                            // 2 MiB sorted bf16 E
    int2*     se   = (int2*)    (ws + 2u * 1024u * 1024u);                // 64 KiB class ranges
    unsigned* hp2  = (unsigned*)(ws + 2u * 1024u * 1024u + 64u * 1024u);  // 32 KiB
    unsigned* hn2  = (unsigned*)(ws + 2u * 1024u * 1024u + 96u * 1024u);  // 32 KiB
    int*      done = (int*)     (ws + 2u * 1024u * 1024u + 128u * 1024u); // 4 B

    hipLaunchKernelGGL(sort_norm, dim3(NCLS), dim3(256), 0, stream, emb, labels, ebf, se, hp2, hn2, done);
    hipLaunchKernelGGL(tri_main,  dim3(NBLK), dim3(256), 0, stream, ebf, se, hp2, hn2, done, out);
}